// Round 1
// baseline (451.738 us; speedup 1.0000x reference)
//
#include <hip/hip_runtime.h>
#include <hip/hip_bf16.h>

#define S 2048
#define D 1024
#define NH 16
#define HD 64
#define NE 65536
#define DH 512

typedef __attribute__((ext_vector_type(8))) short short8;
typedef __attribute__((ext_vector_type(4))) float f32x4;

#define MFMA16(a, b, c) __builtin_amdgcn_mfma_f32_16x16x32_bf16(a, b, c, 0, 0, 0)

__device__ __forceinline__ unsigned short f2bf(float f) {
    __hip_bfloat16 h = __float2bfloat16(f);
    return *reinterpret_cast<unsigned short*>(&h);
}

// ---------------- prep: fp32 -> bf16 conversions ----------------
__global__ __launch_bounds__(256) void k_convert_x(const float* __restrict__ x,
                                                   unsigned short* __restrict__ xb) {
    int i = (blockIdx.x * 256 + threadIdx.x) * 4;
    const float4 v = *reinterpret_cast<const float4*>(x + i);
    xb[i + 0] = f2bf(v.x);
    xb[i + 1] = f2bf(v.y);
    xb[i + 2] = f2bf(v.z);
    xb[i + 3] = f2bf(v.w);
}

// 5 weight slots (2MB bf16 each): 0=Wq 1=Wk 2=Wv 3=Wn1[:, :1024] 4=Wo
__global__ __launch_bounds__(256) void k_convert_w(const float* __restrict__ Wq,
                                                   const float* __restrict__ Wk,
                                                   const float* __restrict__ Wv,
                                                   const float* __restrict__ Wn1,
                                                   const float* __restrict__ Wo,
                                                   unsigned short* __restrict__ wb) {
    int row = blockIdx.x, mat = blockIdx.y, t = threadIdx.x;
    if (mat == 3 && row >= DH) return;
    const float* src;
    long stride = 1024;
    if (mat == 0) src = Wq;
    else if (mat == 1) src = Wk;
    else if (mat == 2) src = Wv;
    else if (mat == 3) { src = Wn1; stride = 1026; }
    else src = Wo;
    const float* r = src + (long)row * stride;
    unsigned short* o = wb + (long)mat * 1048576 + (long)row * 1024;
#pragma unroll
    for (int j = 0; j < 4; j++) o[t * 4 + j] = f2bf(r[t * 4 + j]);
}

// ---------------- stoich mask scatter (numpy last-wins) ----------------
__global__ __launch_bounds__(256) void k_scatter_max(const int* __restrict__ ei,
                                                     int* __restrict__ order) {
    int e = blockIdx.x * 256 + threadIdx.x;
    int r = ei[e], c = ei[NE + e];
    atomicMax(&order[r * S + c], e + 1);
}

__global__ __launch_bounds__(256) void k_scatter_write(const int* __restrict__ ei,
                                                       const float* __restrict__ st,
                                                       const int* __restrict__ order,
                                                       float* __restrict__ mask) {
    int e = blockIdx.x * 256 + threadIdx.x;
    int r = ei[e], c = ei[NE + e];
    int slot = r * S + c;
    if (order[slot] == e + 1) mask[slot] = st[e];
}

// ---------------- fused QKV + hidden GEMM ----------------
// z=0: Q -> [h][s][hd] bf16   z=1: K -> [h][s][hd] bf16
// z=2: V -> [h][hd][s] bf16 (transposed)   z=3: hidden (N=512) -> fp32 [s][512]
__global__ __launch_bounds__(256) void k_gemm_qkvh(const unsigned short* __restrict__ xb,
                                                   const unsigned short* __restrict__ wb,
                                                   const float* __restrict__ bq,
                                                   const float* __restrict__ bk,
                                                   const float* __restrict__ bv,
                                                   const float* __restrict__ bn1,
                                                   unsigned short* __restrict__ qout,
                                                   unsigned short* __restrict__ kout,
                                                   unsigned short* __restrict__ vtout,
                                                   float* __restrict__ hidden) {
    const int z = blockIdx.z;
    if (z == 3 && blockIdx.y >= 8) return;
    const int tid = threadIdx.x, w = tid >> 6, lane = tid & 63;
    const int l15 = lane & 15, lhi = lane >> 4;
    const int m0 = blockIdx.x * 64 + w * 16;
    const int n0 = blockIdx.y * 64;
    const unsigned short* W = wb + (long)z * 1048576;
    f32x4 acc[4];
#pragma unroll
    for (int t = 0; t < 4; t++) acc[t] = (f32x4){0.f, 0.f, 0.f, 0.f};
    const unsigned short* ap0 = xb + (long)(m0 + l15) * 1024 + lhi * 8;
    const unsigned short* bp0 = W + (long)(n0 + l15) * 1024 + lhi * 8;
    for (int kc = 0; kc < 32; kc++) {
        short8 a = *reinterpret_cast<const short8*>(ap0 + kc * 32);
#pragma unroll
        for (int t = 0; t < 4; t++) {
            short8 b = *reinterpret_cast<const short8*>(bp0 + (long)t * 16 * 1024 + kc * 32);
            acc[t] = MFMA16(a, b, acc[t]);
        }
    }
    const float* bias = (z == 0) ? bq : ((z == 1) ? bk : ((z == 2) ? bv : bn1));
#pragma unroll
    for (int t = 0; t < 4; t++) {
        int n = n0 + t * 16 + l15;
        float bb = bias[n];
#pragma unroll
        for (int r = 0; r < 4; r++) {
            int m = m0 + lhi * 4 + r;
            float v = acc[t][r] + bb;
            if (z == 3) {
                hidden[(long)m * DH + n] = v;
            } else {
                unsigned short bits = f2bf(v);
                int hh = n >> 6, hd = n & 63;
                if (z == 0) qout[(long)hh * S * HD + (long)m * HD + hd] = bits;
                else if (z == 1) kout[(long)hh * S * HD + (long)m * HD + hd] = bits;
                else vtout[(long)hh * S * HD + (long)hd * S + m] = bits;
            }
        }
    }
}

// ---------------- node-type MLP tail: tail-cols + relu + logits + softmax ----------------
__global__ __launch_bounds__(256) void k_ntw(const float* __restrict__ hidden,
                                             const float* __restrict__ Wn1,
                                             const float* __restrict__ nt,
                                             const float* __restrict__ Wn2,
                                             const float* __restrict__ bn2,
                                             float* __restrict__ ntw) {
    int s = blockIdx.x, tid = threadIdx.x;
    __shared__ float rh[DH];
    __shared__ float part[16][17];
    float nt0 = nt[s * 2 + 0], nt1 = nt[s * 2 + 1];
    for (int j = tid; j < DH; j += 256) {
        float v = hidden[(long)s * DH + j] + nt0 * Wn1[(long)j * 1026 + 1024]
                + nt1 * Wn1[(long)j * 1026 + 1025];
        rh[j] = fmaxf(v, 0.f);
    }
    __syncthreads();
    {
        int hh = tid & 15, ch = tid >> 4;
        float p = 0.f;
#pragma unroll
        for (int j = 0; j < 32; j++) p += rh[ch * 32 + j] * Wn2[hh * DH + ch * 32 + j];
        part[ch][hh] = p;
    }
    __syncthreads();
    if (tid < 16) {
        float l = bn2[tid];
#pragma unroll
        for (int c = 0; c < 16; c++) l += part[c][tid];
        float mx = l;
#pragma unroll
        for (int m = 1; m < 16; m <<= 1) mx = fmaxf(mx, __shfl_xor(mx, m));
        float e = __expf(l - mx);
        float sum = e;
#pragma unroll
        for (int m = 1; m < 16; m <<= 1) sum += __shfl_xor(sum, m);
        ntw[s * NH + tid] = e / sum;
    }
}

// ---------------- attention: scores+mask+softmax (write attn) + PV ----------------
__global__ __launch_bounds__(256) void k_attn(const unsigned short* __restrict__ qb,
                                              const unsigned short* __restrict__ kb,
                                              const unsigned short* __restrict__ vtb,
                                              const float* __restrict__ ntw,
                                              const float* __restrict__ mask,
                                              float* __restrict__ attn_out,
                                              float* __restrict__ pv_out) {
    extern __shared__ float sm[];
    float* sc = sm;               // [16][2052] padded scores
    float* pvp = sm + 16 * 2052;  // [4][1024] PV partials
    const int tid = threadIdx.x, w = tid >> 6, lane = tid & 63;
    const int l15 = lane & 15, lhi = lane >> 4;
    const int q0 = blockIdx.x * 16, h = blockIdx.y;
    const long hoff = (long)h * S * HD;

    const unsigned short* qp = qb + hoff + (long)(q0 + l15) * HD + lhi * 8;
    short8 a0 = *reinterpret_cast<const short8*>(qp);
    short8 a1 = *reinterpret_cast<const short8*>(qp + 32);

    for (int i = 0; i < 32; i++) {
        int k0 = (i * 4 + w) * 16;
        const unsigned short* kp = kb + hoff + (long)(k0 + l15) * HD + lhi * 8;
        short8 b0 = *reinterpret_cast<const short8*>(kp);
        short8 b1 = *reinterpret_cast<const short8*>(kp + 32);
        f32x4 c = (f32x4){0.f, 0.f, 0.f, 0.f};
        c = MFMA16(a0, b0, c);
        c = MFMA16(a1, b1, c);
        int key = k0 + l15;
        float wnt = 0.125f * ntw[key * NH + h];
#pragma unroll
        for (int r = 0; r < 4; r++) {
            int qr = lhi * 4 + r;
            sc[qr * 2052 + key] = c[r] * wnt * mask[(long)(q0 + qr) * S + key];
        }
    }
    __syncthreads();

#pragma unroll 1
    for (int rr = 0; rr < 4; rr++) {
        int q = w * 4 + rr;
        float* srow = sc + q * 2052;
        float e[32];
        float mx = -3.0e38f;
#pragma unroll
        for (int c2 = 0; c2 < 32; c2++) { e[c2] = srow[c2 * 64 + lane]; mx = fmaxf(mx, e[c2]); }
#pragma unroll
        for (int m = 32; m >= 1; m >>= 1) mx = fmaxf(mx, __shfl_xor(mx, m));
        float sum = 0.f;
#pragma unroll
        for (int c2 = 0; c2 < 32; c2++) { e[c2] = __expf(e[c2] - mx); sum += e[c2]; }
#pragma unroll
        for (int m = 32; m >= 1; m >>= 1) sum += __shfl_xor(sum, m);
        float inv = 1.0f / sum;
        float* arow = attn_out + ((long)h * S + q0 + q) * S;
#pragma unroll
        for (int c2 = 0; c2 < 32; c2++) {
            float a = e[c2] * inv;
            srow[c2 * 64 + lane] = a;
            arow[c2 * 64 + lane] = a;
        }
    }
    __syncthreads();

    f32x4 acc[4];
#pragma unroll
    for (int t = 0; t < 4; t++) acc[t] = (f32x4){0.f, 0.f, 0.f, 0.f};
    for (int kc = 0; kc < 16; kc++) {
        int k0 = w * 512 + kc * 32;
        const float* ap = sc + l15 * 2052 + k0 + lhi * 8;
        short8 a;
#pragma unroll
        for (int j = 0; j < 8; j++) a[j] = (short)f2bf(ap[j]);
#pragma unroll
        for (int t = 0; t < 4; t++) {
            const unsigned short* vp = vtb + hoff + (long)(t * 16 + l15) * S + k0 + lhi * 8;
            short8 b = *reinterpret_cast<const short8*>(vp);
            acc[t] = MFMA16(a, b, acc[t]);
        }
    }
    float* pw = pvp + w * 1024;
#pragma unroll
    for (int t = 0; t < 4; t++)
#pragma unroll
        for (int r = 0; r < 4; r++)
            pw[(lhi * 4 + r) * 64 + t * 16 + l15] = acc[t][r];
    __syncthreads();
#pragma unroll
    for (int u = 0; u < 4; u++) {
        int idx = u * 256 + tid;
        float v = pvp[idx] + pvp[1024 + idx] + pvp[2048 + idx] + pvp[3072 + idx];
        int qr = idx >> 6, hd = idx & 63;
        pv_out[(long)(q0 + qr) * D + h * HD + hd] = v;
    }
}

// ---------------- out projection GEMM (A fp32 -> bf16 on the fly) ----------------
__global__ __launch_bounds__(256) void k_gemm_out(const float* __restrict__ A,
                                                  const unsigned short* __restrict__ wo,
                                                  const float* __restrict__ bo,
                                                  float* __restrict__ proj) {
    const int tid = threadIdx.x, w = tid >> 6, lane = tid & 63;
    const int l15 = lane & 15, lhi = lane >> 4;
    const int m0 = blockIdx.x * 64 + w * 16;
    const int n0 = blockIdx.y * 64;
    f32x4 acc[4];
#pragma unroll
    for (int t = 0; t < 4; t++) acc[t] = (f32x4){0.f, 0.f, 0.f, 0.f};
    const float* ap0 = A + (long)(m0 + l15) * 1024 + lhi * 8;
    const unsigned short* bp0 = wo + (long)(n0 + l15) * 1024 + lhi * 8;
    for (int kc = 0; kc < 32; kc++) {
        const float* ap = ap0 + kc * 32;
        float4 v0 = *reinterpret_cast<const float4*>(ap);
        float4 v1 = *reinterpret_cast<const float4*>(ap + 4);
        short8 a;
        a[0] = f2bf(v0.x); a[1] = f2bf(v0.y); a[2] = f2bf(v0.z); a[3] = f2bf(v0.w);
        a[4] = f2bf(v1.x); a[5] = f2bf(v1.y); a[6] = f2bf(v1.z); a[7] = f2bf(v1.w);
#pragma unroll
        for (int t = 0; t < 4; t++) {
            short8 b = *reinterpret_cast<const short8*>(bp0 + (long)t * 16 * 1024 + kc * 32);
            acc[t] = MFMA16(a, b, acc[t]);
        }
    }
#pragma unroll
    for (int t = 0; t < 4; t++) {
        int n = n0 + t * 16 + l15;
        float bb = bo[n];
#pragma unroll
        for (int r = 0; r < 4; r++) {
            int m = m0 + lhi * 4 + r;
            proj[(long)m * 1024 + n] = acc[t][r] + bb;
        }
    }
}

// ---------------- residual + LayerNorm ----------------
__global__ __launch_bounds__(256) void k_ln(const float* __restrict__ x,
                                            const float* __restrict__ proj,
                                            const float* __restrict__ g,
                                            const float* __restrict__ bta,
                                            float* __restrict__ y) {
    int s = blockIdx.x, tid = threadIdx.x;
    int w = tid >> 6, lane = tid & 63;
    __shared__ float red[8];
    float4 xv = reinterpret_cast<const float4*>(x + (long)s * 1024)[tid];
    float4 pv = reinterpret_cast<const float4*>(proj + (long)s * 1024)[tid];
    float t0 = xv.x + pv.x, t1 = xv.y + pv.y, t2 = xv.z + pv.z, t3 = xv.w + pv.w;
    float lsum = t0 + t1 + t2 + t3;
#pragma unroll
    for (int m = 32; m >= 1; m >>= 1) lsum += __shfl_xor(lsum, m);
    if (lane == 0) red[w] = lsum;
    __syncthreads();
    float mean = (red[0] + red[1] + red[2] + red[3]) * (1.0f / 1024.f);
    float d0 = t0 - mean, d1 = t1 - mean, d2 = t2 - mean, d3 = t3 - mean;
    float lvar = d0 * d0 + d1 * d1 + d2 * d2 + d3 * d3;
#pragma unroll
    for (int m = 32; m >= 1; m >>= 1) lvar += __shfl_xor(lvar, m);
    if (lane == 0) red[4 + w] = lvar;
    __syncthreads();
    float var = (red[4] + red[5] + red[6] + red[7]) * (1.0f / 1024.f);
    float rstd = rsqrtf(var + 1e-5f);
    float4 gv = reinterpret_cast<const float4*>(g)[tid];
    float4 bv = reinterpret_cast<const float4*>(bta)[tid];
    float4 out;
    out.x = d0 * rstd * gv.x + bv.x;
    out.y = d1 * rstd * gv.y + bv.y;
    out.z = d2 * rstd * gv.z + bv.z;
    out.w = d3 * rstd * gv.w + bv.w;
    reinterpret_cast<float4*>(y + (long)s * 1024)[tid] = out;
}

extern "C" void kernel_launch(void* const* d_in, const int* in_sizes, int n_in,
                              void* d_out, int out_size, void* d_ws, size_t ws_size,
                              hipStream_t stream) {
    const float* x = (const float*)d_in[0];
    const float* node_types = (const float*)d_in[1];
    const float* stoich = (const float*)d_in[2];
    const float* Wq = (const float*)d_in[3];
    const float* bq = (const float*)d_in[4];
    const float* Wk = (const float*)d_in[5];
    const float* bk = (const float*)d_in[6];
    const float* Wv = (const float*)d_in[7];
    const float* bv = (const float*)d_in[8];
    const float* Wo = (const float*)d_in[9];
    const float* bo = (const float*)d_in[10];
    const float* Wn1 = (const float*)d_in[11];
    const float* bn1 = (const float*)d_in[12];
    const float* Wn2 = (const float*)d_in[13];
    const float* bn2 = (const float*)d_in[14];
    const float* ln_g = (const float*)d_in[15];
    const float* ln_b = (const float*)d_in[16];
    const int* ei = (const int*)d_in[17];

    char* ws = (char*)d_ws;
    unsigned short* x_bf = (unsigned short*)(ws);               //  0..4M
    unsigned short* q_bf = (unsigned short*)(ws + (4l << 20));  //  4..8M  [h][s][hd]
    unsigned short* k_bf = (unsigned short*)(ws + (8l << 20));  //  8..12M [h][s][hd]
    unsigned short* vt_bf = (unsigned short*)(ws + (12l << 20)); // 12..16M [h][hd][s]
    unsigned short* w_bf = (unsigned short*)(ws + (16l << 20)); // 16..26M 5 slots
    float* hidden = (float*)(ws + (26l << 20));                 // 26..30M
    float* ntwp = (float*)(ws + (30l << 20));                   // 30M (128KB)
    float* mask = (float*)(ws + (31l << 20));                   // 31..47M
    int* order = (int*)(ws + (47l << 20));                      // 47..63M (scatter only)
    float* attnOut = (float*)(ws + (47l << 20));                // 47..55M (aliases order, after scatter)
    float* proj = (float*)(ws + (55l << 20));                   // 55..63M

    float* y_out = (float*)d_out;
    float* attn_out = (float*)d_out + (long)S * D;  // 2097152

    hipMemsetAsync(mask, 0, 16l << 20, stream);
    hipMemsetAsync(order, 0, 16l << 20, stream);
    k_convert_x<<<2048, 256, 0, stream>>>(x, x_bf);
    k_convert_w<<<dim3(1024, 5), 256, 0, stream>>>(Wq, Wk, Wv, Wn1, Wo, w_bf);
    k_scatter_max<<<256, 256, 0, stream>>>(ei, order);
    k_scatter_write<<<256, 256, 0, stream>>>(ei, stoich, order, mask);
    k_gemm_qkvh<<<dim3(32, 16, 4), 256, 0, stream>>>(x_bf, w_bf, bq, bk, bv, bn1,
                                                     q_bf, k_bf, vt_bf, hidden);
    k_ntw<<<2048, 256, 0, stream>>>(hidden, Wn1, node_types, Wn2, bn2, ntwp);
    hipFuncSetAttribute(reinterpret_cast<const void*>(k_attn),
                        hipFuncAttributeMaxDynamicSharedMemorySize, 147712);
    k_attn<<<dim3(128, 16), 256, 147712, stream>>>(q_bf, k_bf, vt_bf, ntwp, mask,
                                                   attn_out, attnOut);
    k_gemm_out<<<dim3(32, 16), 256, 0, stream>>>(attnOut, w_bf + 4l * 1048576, bo, proj);
    k_ln<<<2048, 256, 0, stream>>>(x, proj, ln_g, ln_b, y_out);
}

// Round 2
// 404.538 us; speedup vs baseline: 1.1167x; 1.1167x over previous
//
#include <hip/hip_runtime.h>
#include <hip/hip_bf16.h>

#define S 2048
#define D 1024
#define NH 16
#define HD 64
#define NE 65536
#define DH 512

typedef __attribute__((ext_vector_type(8))) short short8;
typedef __attribute__((ext_vector_type(4))) short short4_t;
typedef __attribute__((ext_vector_type(4))) float f32x4;

#define MFMA16(a, b, c) __builtin_amdgcn_mfma_f32_16x16x32_bf16(a, b, c, 0, 0, 0)

__device__ __forceinline__ unsigned short f2bf(float f) {
    __hip_bfloat16 h = __float2bfloat16(f);
    return *reinterpret_cast<unsigned short*>(&h);
}

// ---------------- prep: fp32 -> bf16 conversions ----------------
__global__ __launch_bounds__(256) void k_convert_x(const float* __restrict__ x,
                                                   unsigned short* __restrict__ xb) {
    int i = (blockIdx.x * 256 + threadIdx.x) * 4;
    const float4 v = *reinterpret_cast<const float4*>(x + i);
    xb[i + 0] = f2bf(v.x);
    xb[i + 1] = f2bf(v.y);
    xb[i + 2] = f2bf(v.z);
    xb[i + 3] = f2bf(v.w);
}

// 5 weight slots (2MB bf16 each): 0=Wq 1=Wk 2=Wv 3=Wn1[:, :1024] 4=Wo
__global__ __launch_bounds__(256) void k_convert_w(const float* __restrict__ Wq,
                                                   const float* __restrict__ Wk,
                                                   const float* __restrict__ Wv,
                                                   const float* __restrict__ Wn1,
                                                   const float* __restrict__ Wo,
                                                   unsigned short* __restrict__ wb) {
    int row = blockIdx.x, mat = blockIdx.y, t = threadIdx.x;
    if (mat == 3 && row >= DH) return;
    const float* src;
    long stride = 1024;
    if (mat == 0) src = Wq;
    else if (mat == 1) src = Wk;
    else if (mat == 2) src = Wv;
    else if (mat == 3) { src = Wn1; stride = 1026; }
    else src = Wo;
    const float* r = src + (long)row * stride;
    unsigned short* o = wb + (long)mat * 1048576 + (long)row * 1024;
#pragma unroll
    for (int j = 0; j < 4; j++) o[t * 4 + j] = f2bf(r[t * 4 + j]);
}

// ---------------- stoich mask scatter (numpy last-wins) ----------------
__global__ __launch_bounds__(256) void k_scatter_max(const int* __restrict__ ei,
                                                     int* __restrict__ order) {
    int e = blockIdx.x * 256 + threadIdx.x;
    int r = ei[e], c = ei[NE + e];
    atomicMax(&order[r * S + c], e + 1);
}

__global__ __launch_bounds__(256) void k_scatter_write(const int* __restrict__ ei,
                                                       const float* __restrict__ st,
                                                       const int* __restrict__ order,
                                                       float* __restrict__ mask) {
    int e = blockIdx.x * 256 + threadIdx.x;
    int r = ei[e], c = ei[NE + e];
    int slot = r * S + c;
    if (order[slot] == e + 1) mask[slot] = st[e];
}

// ---------------- fused QKV + hidden GEMM ----------------
// z=0: Q -> [h][s][hd] bf16   z=1: K -> [h][s][hd] bf16
// z=2: V -> [h][hd][s] bf16 (transposed)   z=3: hidden (N=512) -> fp32 [s][512]
__global__ __launch_bounds__(256) void k_gemm_qkvh(const unsigned short* __restrict__ xb,
                                                   const unsigned short* __restrict__ wb,
                                                   const float* __restrict__ bq,
                                                   const float* __restrict__ bk,
                                                   const float* __restrict__ bv,
                                                   const float* __restrict__ bn1,
                                                   unsigned short* __restrict__ qout,
                                                   unsigned short* __restrict__ kout,
                                                   unsigned short* __restrict__ vtout,
                                                   float* __restrict__ hidden) {
    const int z = blockIdx.z;
    if (z == 3 && blockIdx.y >= 8) return;
    const int tid = threadIdx.x, w = tid >> 6, lane = tid & 63;
    const int l15 = lane & 15, lhi = lane >> 4;
    const int m0 = blockIdx.x * 64 + w * 16;
    const int n0 = blockIdx.y * 64;
    const unsigned short* W = wb + (long)z * 1048576;
    f32x4 acc[4];
#pragma unroll
    for (int t = 0; t < 4; t++) acc[t] = (f32x4){0.f, 0.f, 0.f, 0.f};
    const unsigned short* ap0 = xb + (long)(m0 + l15) * 1024 + lhi * 8;
    const unsigned short* bp0 = W + (long)(n0 + l15) * 1024 + lhi * 8;
    for (int kc = 0; kc < 32; kc++) {
        short8 a = *reinterpret_cast<const short8*>(ap0 + kc * 32);
#pragma unroll
        for (int t = 0; t < 4; t++) {
            short8 b = *reinterpret_cast<const short8*>(bp0 + (long)t * 16 * 1024 + kc * 32);
            acc[t] = MFMA16(a, b, acc[t]);
        }
    }
    const float* bias = (z == 0) ? bq : ((z == 1) ? bk : ((z == 2) ? bv : bn1));
#pragma unroll
    for (int t = 0; t < 4; t++) {
        int n = n0 + t * 16 + l15;
        float bb = bias[n];
#pragma unroll
        for (int r = 0; r < 4; r++) {
            int m = m0 + lhi * 4 + r;
            float v = acc[t][r] + bb;
            if (z == 3) {
                hidden[(long)m * DH + n] = v;
            } else {
                unsigned short bits = f2bf(v);
                int hh = n >> 6, hd = n & 63;
                if (z == 0) qout[(long)hh * S * HD + (long)m * HD + hd] = bits;
                else if (z == 1) kout[(long)hh * S * HD + (long)m * HD + hd] = bits;
                else vtout[(long)hh * S * HD + (long)hd * S + m] = bits;
            }
        }
    }
}

// ---------------- node-type MLP tail -> ntwT [h][s] (transposed for attention) ----------------
__global__ __launch_bounds__(256) void k_ntw(const float* __restrict__ hidden,
                                             const float* __restrict__ Wn1,
                                             const float* __restrict__ nt,
                                             const float* __restrict__ Wn2,
                                             const float* __restrict__ bn2,
                                             float* __restrict__ ntwT) {
    int s = blockIdx.x, tid = threadIdx.x;
    __shared__ float rh[DH];
    __shared__ float part[16][17];
    float nt0 = nt[s * 2 + 0], nt1 = nt[s * 2 + 1];
    for (int j = tid; j < DH; j += 256) {
        float v = hidden[(long)s * DH + j] + nt0 * Wn1[(long)j * 1026 + 1024]
                + nt1 * Wn1[(long)j * 1026 + 1025];
        rh[j] = fmaxf(v, 0.f);
    }
    __syncthreads();
    {
        int hh = tid & 15, ch = tid >> 4;
        float p = 0.f;
#pragma unroll
        for (int j = 0; j < 32; j++) p += rh[ch * 32 + j] * Wn2[hh * DH + ch * 32 + j];
        part[ch][hh] = p;
    }
    __syncthreads();
    if (tid < 16) {
        float l = bn2[tid];
#pragma unroll
        for (int c = 0; c < 16; c++) l += part[c][tid];
        float mx = l;
#pragma unroll
        for (int m = 1; m < 16; m <<= 1) mx = fmaxf(mx, __shfl_xor(mx, m));
        float e = __expf(l - mx);
        float sum = e;
#pragma unroll
        for (int m = 1; m < 16; m <<= 1) sum += __shfl_xor(sum, m);
        ntwT[tid * S + s] = e / sum;
    }
}

// ---------------- attention: swapped QK^T, register-resident scores ----------------
// Block: 16 q-rows (blockIdx.x) x 1 head (blockIdx.y), 4 waves; wave w owns keys
// [w*512, w*512+512). Swapped MFMA(K,Q): lane holds q = lane&15,
// keys = k0 + 4*(lane>>4) + r. Scores stay in 128 VGPRs; softmax via shfl + tiny
// LDS; P transposed to MFMA A-frags through a 1KB/wave LDS scratch; per-wave
// partial PV reduced through padded LDS.
__global__ __launch_bounds__(256, 2) void k_attn(const unsigned short* __restrict__ qb,
                                                 const unsigned short* __restrict__ kb,
                                                 const unsigned short* __restrict__ vtb,
                                                 const float* __restrict__ ntwT,
                                                 const float* __restrict__ mask,
                                                 float* __restrict__ attn_out,
                                                 float* __restrict__ pv_out) {
    __shared__ unsigned short pscr[4][16][32];  // per-wave P transpose scratch
    __shared__ float pvp[4][16][65];            // per-wave PV partials (padded)
    __shared__ float redmx[4][16];
    __shared__ float redsm[4][16];

    const int tid = threadIdx.x, w = tid >> 6, lane = tid & 63;
    const int l15 = lane & 15, lhi = lane >> 4;
    const int q0 = blockIdx.x * 16, h = blockIdx.y;
    const long hoff = (long)h * S * HD;

    // Q as B-operand: lane holds Q[q = q0+l15][hd = 8*lhi .. +7] (+32 for 2nd k-chunk)
    const unsigned short* qp = qb + hoff + (long)(q0 + l15) * HD + lhi * 8;
    const short8 qf0 = *reinterpret_cast<const short8*>(qp);
    const short8 qf1 = *reinterpret_cast<const short8*>(qp + 32);

    const unsigned short* kbase = kb + hoff + (long)l15 * HD + lhi * 8;
    const float* mrow = mask + (long)(q0 + l15) * S + 4 * lhi;
    const float* ntrow = ntwT + (long)h * S + 4 * lhi;

    f32x4 sc[32];
#pragma unroll
    for (int t = 0; t < 32; t++) {
        const int k0 = w * 512 + t * 16;
        const unsigned short* kp = kbase + (long)k0 * HD;
        short8 kf0 = *reinterpret_cast<const short8*>(kp);
        short8 kf1 = *reinterpret_cast<const short8*>(kp + 32);
        f32x4 c = (f32x4){0.f, 0.f, 0.f, 0.f};
        c = MFMA16(kf0, qf0, c);
        c = MFMA16(kf1, qf1, c);
        f32x4 m4 = *reinterpret_cast<const f32x4*>(mrow + k0);
        f32x4 n4 = *reinterpret_cast<const f32x4*>(ntrow + k0);
        sc[t] = c * m4 * n4 * 0.125f;
    }

    // per-wave max over this wave's 512 keys for q = l15
    float mx = -3.0e38f;
#pragma unroll
    for (int t = 0; t < 32; t++) {
        mx = fmaxf(mx, fmaxf(fmaxf(sc[t][0], sc[t][1]), fmaxf(sc[t][2], sc[t][3])));
    }
    mx = fmaxf(mx, __shfl_xor(mx, 16));
    mx = fmaxf(mx, __shfl_xor(mx, 32));
    if (lane < 16) redmx[w][lane] = mx;
    __syncthreads();
    const float gmx = fmaxf(fmaxf(redmx[0][l15], redmx[1][l15]),
                            fmaxf(redmx[2][l15], redmx[3][l15]));

    float sum = 0.f;
#pragma unroll
    for (int t = 0; t < 32; t++) {
        f32x4 e;
        e[0] = __expf(sc[t][0] - gmx);
        e[1] = __expf(sc[t][1] - gmx);
        e[2] = __expf(sc[t][2] - gmx);
        e[3] = __expf(sc[t][3] - gmx);
        sc[t] = e;
        sum += (e[0] + e[1]) + (e[2] + e[3]);
    }
    sum += __shfl_xor(sum, 16);
    sum += __shfl_xor(sum, 32);
    if (lane < 16) redsm[w][lane] = sum;
    __syncthreads();
    const float inv = 1.0f / (redsm[0][l15] + redsm[1][l15] + redsm[2][l15] + redsm[3][l15]);

    // normalize + write attn (float4, 4 consecutive keys) + PV over 32-key chunks
    float* arow = attn_out + ((long)h * S + q0 + l15) * S + 4 * lhi;
    const unsigned short* vbase = vtb + hoff + (long)l15 * S + 8 * lhi;
    f32x4 acc[4];
#pragma unroll
    for (int t = 0; t < 4; t++) acc[t] = (f32x4){0.f, 0.f, 0.f, 0.f};

#pragma unroll
    for (int cc = 0; cc < 16; cc++) {
        f32x4 p0 = sc[2 * cc] * inv;
        f32x4 p1 = sc[2 * cc + 1] * inv;
        const int k0 = w * 512 + cc * 32;
        *reinterpret_cast<f32x4*>(arow + k0) = p0;
        *reinterpret_cast<f32x4*>(arow + k0 + 16) = p1;
        short4_t pk0, pk1;
#pragma unroll
        for (int j = 0; j < 4; j++) {
            pk0[j] = (short)f2bf(p0[j]);
            pk1[j] = (short)f2bf(p1[j]);
        }
        // transpose through per-wave scratch: write [q=l15][key-in-chunk]
        *reinterpret_cast<short4_t*>(&pscr[w][l15][4 * lhi]) = pk0;
        *reinterpret_cast<short4_t*>(&pscr[w][l15][16 + 4 * lhi]) = pk1;
        // A-frag: lane holds P[q=l15][keys 8*lhi .. +7]
        short8 pa = *reinterpret_cast<const short8*>(&pscr[w][l15][8 * lhi]);
#pragma unroll
        for (int t2 = 0; t2 < 4; t2++) {
            short8 vf = *reinterpret_cast<const short8*>(vbase + (long)t2 * 16 * S + k0);
            acc[t2] = MFMA16(pa, vf, acc[t2]);
        }
    }

    // per-wave PV partials -> LDS -> reduce
#pragma unroll
    for (int t2 = 0; t2 < 4; t2++)
#pragma unroll
        for (int r = 0; r < 4; r++)
            pvp[w][4 * lhi + r][t2 * 16 + l15] = acc[t2][r];
    __syncthreads();
#pragma unroll
    for (int u = 0; u < 4; u++) {
        int idx = u * 256 + tid;
        int q = idx >> 6, hd = idx & 63;
        float v = pvp[0][q][hd] + pvp[1][q][hd] + pvp[2][q][hd] + pvp[3][q][hd];
        pv_out[(long)(q0 + q) * D + h * HD + hd] = v;
    }
}

// ---------------- out projection GEMM (A fp32 -> bf16 on the fly) ----------------
__global__ __launch_bounds__(256) void k_gemm_out(const float* __restrict__ A,
                                                  const unsigned short* __restrict__ wo,
                                                  const float* __restrict__ bo,
                                                  float* __restrict__ proj) {
    const int tid = threadIdx.x, w = tid >> 6, lane = tid & 63;
    const int l15 = lane & 15, lhi = lane >> 4;
    const int m0 = blockIdx.x * 64 + w * 16;
    const int n0 = blockIdx.y * 64;
    f32x4 acc[4];
#pragma unroll
    for (int t = 0; t < 4; t++) acc[t] = (f32x4){0.f, 0.f, 0.f, 0.f};
    const float* ap0 = A + (long)(m0 + l15) * 1024 + lhi * 8;
    const unsigned short* bp0 = wo + (long)(n0 + l15) * 1024 + lhi * 8;
    for (int kc = 0; kc < 32; kc++) {
        const float* ap = ap0 + kc * 32;
        float4 v0 = *reinterpret_cast<const float4*>(ap);
        float4 v1 = *reinterpret_cast<const float4*>(ap + 4);
        short8 a;
        a[0] = f2bf(v0.x); a[1] = f2bf(v0.y); a[2] = f2bf(v0.z); a[3] = f2bf(v0.w);
        a[4] = f2bf(v1.x); a[5] = f2bf(v1.y); a[6] = f2bf(v1.z); a[7] = f2bf(v1.w);
#pragma unroll
        for (int t = 0; t < 4; t++) {
            short8 b = *reinterpret_cast<const short8*>(bp0 + (long)t * 16 * 1024 + kc * 32);
            acc[t] = MFMA16(a, b, acc[t]);
        }
    }
#pragma unroll
    for (int t = 0; t < 4; t++) {
        int n = n0 + t * 16 + l15;
        float bb = bo[n];
#pragma unroll
        for (int r = 0; r < 4; r++) {
            int m = m0 + lhi * 4 + r;
            proj[(long)m * 1024 + n] = acc[t][r] + bb;
        }
    }
}

// ---------------- residual + LayerNorm ----------------
__global__ __launch_bounds__(256) void k_ln(const float* __restrict__ x,
                                            const float* __restrict__ proj,
                                            const float* __restrict__ g,
                                            const float* __restrict__ bta,
                                            float* __restrict__ y) {
    int s = blockIdx.x, tid = threadIdx.x;
    int w = tid >> 6, lane = tid & 63;
    __shared__ float red[8];
    float4 xv = reinterpret_cast<const float4*>(x + (long)s * 1024)[tid];
    float4 pv = reinterpret_cast<const float4*>(proj + (long)s * 1024)[tid];
    float t0 = xv.x + pv.x, t1 = xv.y + pv.y, t2 = xv.z + pv.z, t3 = xv.w + pv.w;
    float lsum = t0 + t1 + t2 + t3;
#pragma unroll
    for (int m = 32; m >= 1; m >>= 1) lsum += __shfl_xor(lsum, m);
    if (lane == 0) red[w] = lsum;
    __syncthreads();
    float mean = (red[0] + red[1] + red[2] + red[3]) * (1.0f / 1024.f);
    float d0 = t0 - mean, d1 = t1 - mean, d2 = t2 - mean, d3 = t3 - mean;
    float lvar = d0 * d0 + d1 * d1 + d2 * d2 + d3 * d3;
#pragma unroll
    for (int m = 32; m >= 1; m >>= 1) lvar += __shfl_xor(lvar, m);
    if (lane == 0) red[4 + w] = lvar;
    __syncthreads();
    float var = (red[4] + red[5] + red[6] + red[7]) * (1.0f / 1024.f);
    float rstd = rsqrtf(var + 1e-5f);
    float4 gv = reinterpret_cast<const float4*>(g)[tid];
    float4 bv = reinterpret_cast<const float4*>(bta)[tid];
    float4 out;
    out.x = d0 * rstd * gv.x + bv.x;
    out.y = d1 * rstd * gv.y + bv.y;
    out.z = d2 * rstd * gv.z + bv.z;
    out.w = d3 * rstd * gv.w + bv.w;
    reinterpret_cast<float4*>(y + (long)s * 1024)[tid] = out;
}

extern "C" void kernel_launch(void* const* d_in, const int* in_sizes, int n_in,
                              void* d_out, int out_size, void* d_ws, size_t ws_size,
                              hipStream_t stream) {
    const float* x = (const float*)d_in[0];
    const float* node_types = (const float*)d_in[1];
    const float* stoich = (const float*)d_in[2];
    const float* Wq = (const float*)d_in[3];
    const float* bq = (const float*)d_in[4];
    const float* Wk = (const float*)d_in[5];
    const float* bk = (const float*)d_in[6];
    const float* Wv = (const float*)d_in[7];
    const float* bv = (const float*)d_in[8];
    const float* Wo = (const float*)d_in[9];
    const float* bo = (const float*)d_in[10];
    const float* Wn1 = (const float*)d_in[11];
    const float* bn1 = (const float*)d_in[12];
    const float* Wn2 = (const float*)d_in[13];
    const float* bn2 = (const float*)d_in[14];
    const float* ln_g = (const float*)d_in[15];
    const float* ln_b = (const float*)d_in[16];
    const int* ei = (const int*)d_in[17];

    char* ws = (char*)d_ws;
    unsigned short* x_bf = (unsigned short*)(ws);               //  0..4M
    unsigned short* q_bf = (unsigned short*)(ws + (4l << 20));  //  4..8M  [h][s][hd]
    unsigned short* k_bf = (unsigned short*)(ws + (8l << 20));  //  8..12M [h][s][hd]
    unsigned short* vt_bf = (unsigned short*)(ws + (12l << 20)); // 12..16M [h][hd][s]
    unsigned short* w_bf = (unsigned short*)(ws + (16l << 20)); // 16..26M 5 slots
    float* hidden = (float*)(ws + (26l << 20));                 // 26..30M
    float* ntwT = (float*)(ws + (30l << 20));                   // 30M (128KB) [h][s]
    float* mask = (float*)(ws + (31l << 20));                   // 31..47M
    int* order = (int*)(ws + (47l << 20));                      // 47..63M (scatter only)
    float* attnOut = (float*)(ws + (47l << 20));                // 47..55M (aliases order, after scatter)
    float* proj = (float*)(ws + (55l << 20));                   // 55..63M

    float* y_out = (float*)d_out;
    float* attn_out = (float*)d_out + (long)S * D;  // 2097152

    hipMemsetAsync(mask, 0, 16l << 20, stream);
    hipMemsetAsync(order, 0, 16l << 20, stream);
    k_convert_x<<<2048, 256, 0, stream>>>(x, x_bf);
    k_convert_w<<<dim3(1024, 5), 256, 0, stream>>>(Wq, Wk, Wv, Wn1, Wo, w_bf);
    k_scatter_max<<<256, 256, 0, stream>>>(ei, order);
    k_scatter_write<<<256, 256, 0, stream>>>(ei, stoich, order, mask);
    k_gemm_qkvh<<<dim3(32, 16, 4), 256, 0, stream>>>(x_bf, w_bf, bq, bk, bv, bn1,
                                                     q_bf, k_bf, vt_bf, hidden);
    k_ntw<<<2048, 256, 0, stream>>>(hidden, Wn1, node_types, Wn2, bn2, ntwT);
    k_attn<<<dim3(128, 16), 256, 0, stream>>>(q_bf, k_bf, vt_bf, ntwT, mask,
                                              attn_out, attnOut);
    k_gemm_out<<<dim3(32, 16), 256, 0, stream>>>(attnOut, w_bf + 4l * 1048576, bo, proj);
    k_ln<<<2048, 256, 0, stream>>>(x, proj, ln_g, ln_b, y_out);
}